// Round 1
// baseline (1001.764 us; speedup 1.0000x reference)
//
#include <hip/hip_runtime.h>
#include <math.h>

#define N_NODES 50000
#define N_EDGES 800000
#define D_IN 256
#define D_HID 128
#define ALPHA 0.1f
#define EPS 1e-5f

// ---------------- CSR build ----------------
__global__ void k_count(const int* __restrict__ dst, int* __restrict__ cnt, int e) {
    int i = blockIdx.x * 256 + threadIdx.x;
    if (i < e) atomicAdd(&cnt[dst[i]], 1);
}

__global__ __launch_bounds__(1024) void k_scan(const int* __restrict__ cnt, int* __restrict__ rp,
                                               int* __restrict__ fill, float* __restrict__ dinv,
                                               int n) {
    __shared__ int sh[1024];
    int t = threadIdx.x;
    int carry = 0;
    for (int base = 0; base < n; base += 1024) {
        int i = base + t;
        int v = (i < n) ? cnt[i] : 0;
        sh[t] = v;
        __syncthreads();
        for (int ofs = 1; ofs < 1024; ofs <<= 1) {
            int y = 0;
            if (t >= ofs) y = sh[t - ofs];
            __syncthreads();
            sh[t] += y;
            __syncthreads();
        }
        int incl = sh[t];
        int total = sh[1023];
        if (i < n) {
            int ex = carry + incl - v;
            rp[i] = ex;
            fill[i] = ex;
            dinv[i] = rsqrtf((float)(v + 1));  // deg = in_deg + self-loop
        }
        carry += total;
        __syncthreads();
    }
    if (t == 0) rp[n] = carry;
}

__global__ void k_fill(const int* __restrict__ src, const int* __restrict__ dst,
                       int* __restrict__ fill, int* __restrict__ cs, int e) {
    int i = blockIdx.x * 256 + threadIdx.x;
    if (i < e) {
        int d = dst[i];
        int p = atomicAdd(&fill[d], 1);
        cs[p] = src[i];
    }
}

// ---------------- GEMM: out[r][c] = sum_k A[r][k]*B[k][c], fused epilogues ----------------
// MODE 0: plain store (xw = x @ W_lin)
// MODE 1: combine: val=(1-beta)*H + beta*acc, store, accumulate BN column sums
// MODE 2: combine, no BN stats (final layer)
template <int K, int MODE>
__global__ __launch_bounds__(256) void k_gemm(const float* __restrict__ A, const float* __restrict__ B,
                                              float* __restrict__ out, const float* __restrict__ H,
                                              float betaC, float* __restrict__ bn_s,
                                              float* __restrict__ bn_q, int n) {
    __shared__ float lds_a[64 * 33];
    __shared__ float lds_b[32 * 128];
    int t = threadIdx.x;
    int tx = t & 31;          // column group: cols tx*4..tx*4+3
    int ty = t >> 5;          // row group: rows ty*8..ty*8+7
    int row0 = blockIdx.x * 64;

    float4 acc[8];
#pragma unroll
    for (int j = 0; j < 8; ++j) acc[j] = make_float4(0.f, 0.f, 0.f, 0.f);

    int lrow = t >> 2, lq = t & 3;       // A-chunk loader: 64 rows x 32 k
    int brow = t >> 3, bq = t & 7;       // B-chunk loader: 32 k x 128 c
    float4* lb4 = (float4*)lds_b;

    for (int k0 = 0; k0 < K; k0 += 32) {
        float4 va0 = make_float4(0.f, 0.f, 0.f, 0.f), va1 = va0;
        int gr = row0 + lrow;
        if (gr < n) {
            const float4* ap = (const float4*)(A + (size_t)gr * K + k0 + lq * 8);
            va0 = ap[0];
            va1 = ap[1];
        }
        float4 vb[4];
        const float4* bp = (const float4*)(B + (size_t)(k0 + brow) * 128 + bq * 16);
#pragma unroll
        for (int u = 0; u < 4; ++u) vb[u] = bp[u];

        __syncthreads();
        float* aw = &lds_a[lrow * 33 + lq * 8];
        aw[0] = va0.x; aw[1] = va0.y; aw[2] = va0.z; aw[3] = va0.w;
        aw[4] = va1.x; aw[5] = va1.y; aw[6] = va1.z; aw[7] = va1.w;
#pragma unroll
        for (int u = 0; u < 4; ++u) lb4[brow * 32 + bq * 4 + u] = vb[u];
        __syncthreads();

#pragma unroll
        for (int kk = 0; kk < 32; ++kk) {
            float4 b4 = lb4[kk * 32 + tx];
#pragma unroll
            for (int j = 0; j < 8; ++j) {
                float a = lds_a[(ty * 8 + j) * 33 + kk];
                acc[j].x = fmaf(a, b4.x, acc[j].x);
                acc[j].y = fmaf(a, b4.y, acc[j].y);
                acc[j].z = fmaf(a, b4.z, acc[j].z);
                acc[j].w = fmaf(a, b4.w, acc[j].w);
            }
        }
    }

    if (MODE == 0) {
#pragma unroll
        for (int j = 0; j < 8; ++j) {
            int r = row0 + ty * 8 + j;
            if (r < n) *(float4*)(out + (size_t)r * 128 + tx * 4) = acc[j];
        }
    } else {
        float sum[4] = {0.f, 0.f, 0.f, 0.f};
        float sq[4] = {0.f, 0.f, 0.f, 0.f};
        float omb = 1.0f - betaC;
#pragma unroll
        for (int j = 0; j < 8; ++j) {
            int r = row0 + ty * 8 + j;
            if (r < n) {
                float4 hv = *(const float4*)(H + (size_t)r * 128 + tx * 4);
                float4 val;
                val.x = fmaf(omb, hv.x, betaC * acc[j].x);
                val.y = fmaf(omb, hv.y, betaC * acc[j].y);
                val.z = fmaf(omb, hv.z, betaC * acc[j].z);
                val.w = fmaf(omb, hv.w, betaC * acc[j].w);
                *(float4*)(out + (size_t)r * 128 + tx * 4) = val;
                if (MODE == 1) {
                    sum[0] += val.x; sum[1] += val.y; sum[2] += val.z; sum[3] += val.w;
                    sq[0] += val.x * val.x; sq[1] += val.y * val.y;
                    sq[2] += val.z * val.z; sq[3] += val.w * val.w;
                }
            }
        }
        if (MODE == 1) {
            __syncthreads();
            float* rs = lds_b;            // [8][128]
            float* rq = lds_b + 1024;     // [8][128]
#pragma unroll
            for (int u = 0; u < 4; ++u) {
                rs[ty * 128 + tx * 4 + u] = sum[u];
                rq[ty * 128 + tx * 4 + u] = sq[u];
            }
            __syncthreads();
            if (t < 128) {
                float s = 0.f, q = 0.f;
#pragma unroll
                for (int y = 0; y < 8; ++y) {
                    s += rs[y * 128 + t];
                    q += rq[y * 128 + t];
                }
                atomicAdd(bn_s + t, s);
                atomicAdd(bn_q + t, q);
            }
        }
    }
}

// ---------------- GCNConv aggregation (weighted, self-loop, +bias) ----------------
__global__ __launch_bounds__(256) void k_agg_gcn(const float2* __restrict__ xw2,
                                                 const float* __restrict__ dinv,
                                                 const int* __restrict__ rp, const int* __restrict__ cs,
                                                 const float* __restrict__ b_lin,
                                                 float2* __restrict__ x02, int n) {
    int wid = (blockIdx.x * 256 + threadIdx.x) >> 6;
    int lane = threadIdx.x & 63;
    if (wid >= n) return;
    float dn = dinv[wid];
    int start = rp[wid], end = rp[wid + 1];
    float ax = 0.f, ay = 0.f;
    for (int j = start; j < end; ++j) {
        int s = cs[j];
        float w = dinv[s] * dn;
        float2 v = xw2[(size_t)s * 64 + lane];
        ax = fmaf(w, v.x, ax);
        ay = fmaf(w, v.y, ay);
    }
    float2 vs = xw2[(size_t)wid * 64 + lane];
    float w2 = dn * dn;
    ax = fmaf(w2, vs.x, ax);
    ay = fmaf(w2, vs.y, ay);
    float2 bb = ((const float2*)b_lin)[lane];
    float2 o;
    o.x = ax + bb.x;
    o.y = ay + bb.y;
    x02[(size_t)wid * 64 + lane] = o;
}

// ---------------- GCN2 aggregation: h = 0.9*sum_j f(z[src]) + 0.1*x0 ----------------
// BN=1: f(z) = relu(s*z + t); BN=0: identity
template <int BN>
__global__ __launch_bounds__(256) void k_agg2(const float2* __restrict__ z2,
                                              const float2* __restrict__ x02,
                                              const int* __restrict__ rp, const int* __restrict__ cs,
                                              const float* __restrict__ st, float2* __restrict__ h2,
                                              int n) {
    int wid = (blockIdx.x * 256 + threadIdx.x) >> 6;
    int lane = threadIdx.x & 63;
    if (wid >= n) return;
    float2 sc, tc;
    if (BN) {
        sc = ((const float2*)st)[lane];
        tc = ((const float2*)st)[64 + lane];
    }
    int start = rp[wid], end = rp[wid + 1];
    float ax = 0.f, ay = 0.f;
    for (int j = start; j < end; ++j) {
        int s = cs[j];
        float2 v = z2[(size_t)s * 64 + lane];
        if (BN) {
            v.x = fmaxf(fmaf(sc.x, v.x, tc.x), 0.f);
            v.y = fmaxf(fmaf(sc.y, v.y, tc.y), 0.f);
        }
        ax += v.x;
        ay += v.y;
    }
    float2 x0v = x02[(size_t)wid * 64 + lane];
    float2 o;
    o.x = fmaf(ALPHA, x0v.x, (1.0f - ALPHA) * ax);
    o.y = fmaf(ALPHA, x0v.y, (1.0f - ALPHA) * ay);
    h2[(size_t)wid * 64 + lane] = o;
}

// ---------------- BN finalize: s = gamma*rsqrt(var+eps), t = beta - mu*s ----------------
__global__ void k_bn_fin(const float* __restrict__ bn_s, const float* __restrict__ bn_q,
                         const float* __restrict__ gamma, const float* __restrict__ betap,
                         float* __restrict__ st, int n) {
    int c = threadIdx.x;
    float inv_n = 1.0f / (float)n;
    float mu = bn_s[c] * inv_n;
    float var = bn_q[c] * inv_n - mu * mu;
    var = fmaxf(var, 0.f);
    float s = gamma[c] * rsqrtf(var + EPS);
    st[c] = s;
    st[128 + c] = betap[c] - mu * s;
}

extern "C" void kernel_launch(void* const* d_in, const int* in_sizes, int n_in,
                              void* d_out, int out_size, void* d_ws, size_t ws_size,
                              hipStream_t stream) {
    const float* x = (const float*)d_in[0];
    const int* ei = (const int*)d_in[1];        // [2][E]: src row, dst row
    const float* W_lin = (const float*)d_in[2];
    const float* b_lin = (const float*)d_in[3];
    const float* W1s = (const float*)d_in[4];
    const float* gam = (const float*)d_in[5];
    const float* betp = (const float*)d_in[6];
    float* out = (float*)d_out;

    char* ws = (char*)d_ws;
    size_t off = 0;
    auto alloc = [&](size_t b) { size_t p = off; off = (off + b + 255) & ~(size_t)255; return p; };
    int* cnt = (int*)(ws + alloc((size_t)N_NODES * 4));
    int* rp = (int*)(ws + alloc((size_t)(N_NODES + 1) * 4));
    int* fill = (int*)(ws + alloc((size_t)N_NODES * 4));
    int* cs = (int*)(ws + alloc((size_t)N_EDGES * 4));
    float* dinv = (float*)(ws + alloc((size_t)N_NODES * 4));
    float* xw = (float*)(ws + alloc((size_t)N_NODES * D_HID * 4));
    float* x0 = (float*)(ws + alloc((size_t)N_NODES * D_HID * 4));
    float* z = (float*)(ws + alloc((size_t)N_NODES * D_HID * 4));
    float* h = (float*)(ws + alloc((size_t)N_NODES * D_HID * 4));
    float* bns = (float*)(ws + alloc(256 * 4));   // [0:128) sum, [128:256) sumsq
    float* st = (float*)(ws + alloc(256 * 4));    // [0:128) scale, [128:256) shift

    const int egrid = (N_EDGES + 255) / 256;
    const int ggrid = (N_NODES + 63) / 64;       // 782
    const int agrid = (N_NODES + 3) / 4;         // 12500 (4 waves/block)

    // CSR build
    hipMemsetAsync(cnt, 0, (size_t)N_NODES * 4, stream);
    k_count<<<egrid, 256, 0, stream>>>(ei + N_EDGES, cnt, N_EDGES);
    k_scan<<<1, 1024, 0, stream>>>(cnt, rp, fill, dinv, N_NODES);
    k_fill<<<egrid, 256, 0, stream>>>(ei, ei + N_EDGES, fill, cs, N_EDGES);

    // GCNConv: xw = x @ W_lin; then normalized aggregation + bias -> x0
    k_gemm<D_IN, 0><<<ggrid, 256, 0, stream>>>(x, W_lin, xw, nullptr, 0.f, nullptr, nullptr, N_NODES);
    k_agg_gcn<<<agrid, 256, 0, stream>>>((const float2*)xw, dinv, rp, cs, b_lin, (float2*)x0, N_NODES);

    // 5x GCN2Conv (+BN/ReLU fused into next gather)
    for (int i = 0; i < 5; ++i) {
        float bet = (float)log(0.5 / (double)(i + 1) + 1.0);
        const float* zsrc = (i == 0) ? x0 : z;
        if (i == 0)
            k_agg2<0><<<agrid, 256, 0, stream>>>((const float2*)zsrc, (const float2*)x0, rp, cs,
                                                 nullptr, (float2*)h, N_NODES);
        else
            k_agg2<1><<<agrid, 256, 0, stream>>>((const float2*)zsrc, (const float2*)x0, rp, cs,
                                                 st, (float2*)h, N_NODES);
        const float* W1 = W1s + (size_t)i * D_HID * D_HID;
        if (i < 4) {
            hipMemsetAsync(bns, 0, 256 * 4, stream);
            k_gemm<D_HID, 1><<<ggrid, 256, 0, stream>>>(h, W1, z, h, bet, bns, bns + 128, N_NODES);
            k_bn_fin<<<1, 128, 0, stream>>>(bns, bns + 128, gam + (size_t)i * 128,
                                            betp + (size_t)i * 128, st, N_NODES);
        } else {
            k_gemm<D_HID, 2><<<ggrid, 256, 0, stream>>>(h, W1, out, h, bet, nullptr, nullptr, N_NODES);
        }
    }
}

// Round 2
// 587.315 us; speedup vs baseline: 1.7057x; 1.7057x over previous
//
#include <hip/hip_runtime.h>
#include <math.h>

#define N_NODES 50000
#define N_EDGES 800000
#define D_IN 256
#define D_HID 128
#define ALPHA 0.1f
#define EPS 1e-5f

typedef __attribute__((ext_vector_type(8))) short bf16x8;
typedef __attribute__((ext_vector_type(4))) float f32x4;

static __device__ __forceinline__ float bf2f(unsigned short u) {
    return __uint_as_float(((unsigned int)u) << 16);
}
static __device__ __forceinline__ unsigned short f2bf(float f) {
    unsigned int x = __float_as_uint(f);
    return (unsigned short)((x + 0x7fffu + ((x >> 16) & 1u)) >> 16);
}

// ---------------- CSR build ----------------
__global__ void k_count(const int* __restrict__ dst, int* __restrict__ cnt, int e) {
    int i = blockIdx.x * 256 + threadIdx.x;
    if (i < e) atomicAdd(&cnt[dst[i]], 1);
}

// block sums of cnt (256 per block)
__global__ __launch_bounds__(256) void k_bsum(const int* __restrict__ cnt, int* __restrict__ bsum, int n) {
    __shared__ int sh[256];
    int t = threadIdx.x;
    int i = blockIdx.x * 256 + t;
    sh[t] = (i < n) ? cnt[i] : 0;
    __syncthreads();
    for (int ofs = 128; ofs > 0; ofs >>= 1) {
        if (t < ofs) sh[t] += sh[t + ofs];
        __syncthreads();
    }
    if (t == 0) bsum[blockIdx.x] = sh[0];
}

// scan the (<=256) block sums
__global__ __launch_bounds__(256) void k_bscan(const int* __restrict__ bsum, int* __restrict__ boff,
                                               int* __restrict__ rp, int nblk, int n) {
    __shared__ int sh[256];
    int t = threadIdx.x;
    int v = (t < nblk) ? bsum[t] : 0;
    sh[t] = v;
    __syncthreads();
    for (int ofs = 1; ofs < 256; ofs <<= 1) {
        int y = (t >= ofs) ? sh[t - ofs] : 0;
        __syncthreads();
        sh[t] += y;
        __syncthreads();
    }
    if (t < nblk) boff[t] = sh[t] - v;
    if (t == 255) rp[n] = sh[255];
}

// per-block exclusive scan + block offset -> rp, fill, dinv
__global__ __launch_bounds__(256) void k_scan2(const int* __restrict__ cnt, const int* __restrict__ boff,
                                               int* __restrict__ rp, int* __restrict__ fill,
                                               float* __restrict__ dinv, int n) {
    __shared__ int sh[256];
    int t = threadIdx.x;
    int i = blockIdx.x * 256 + t;
    int v = (i < n) ? cnt[i] : 0;
    sh[t] = v;
    __syncthreads();
    for (int ofs = 1; ofs < 256; ofs <<= 1) {
        int y = (t >= ofs) ? sh[t - ofs] : 0;
        __syncthreads();
        sh[t] += y;
        __syncthreads();
    }
    if (i < n) {
        int ex = boff[blockIdx.x] + sh[t] - v;
        rp[i] = ex;
        fill[i] = ex;
        dinv[i] = rsqrtf((float)(v + 1));
    }
}

__global__ void k_fill(const int* __restrict__ src, const int* __restrict__ dst,
                       int* __restrict__ fill, int* __restrict__ cs, int e) {
    int i = blockIdx.x * 256 + threadIdx.x;
    if (i < e) {
        int d = dst[i];
        int p = atomicAdd(&fill[d], 1);
        cs[p] = src[i];
    }
}

// ---------------- prep: cast x to bf16 ----------------
__global__ __launch_bounds__(256) void k_cast_x(const float4* __restrict__ x, ushort2* __restrict__ xb,
                                                int n4) {
    int i = blockIdx.x * 256 + threadIdx.x;
    if (i < n4) {
        float4 v = x[i];
        ushort2 a;
        a.x = f2bf(v.x); a.y = f2bf(v.y);
        ushort2 b;
        b.x = f2bf(v.z); b.y = f2bf(v.w);
        ((ushort2*)xb)[i * 2] = a;
        ((ushort2*)xb)[i * 2 + 1] = b;
    }
}

// ---------------- prep weights: transposed bf16; fold (1-beta)I + beta*W1 ----------------
// Wlt[c][k] = W_lin[k][c]  (c<128, k<256)
// Wt[l][c][k] = (1-beta_l)*(c==k) + beta_l*W1s[l][k][c]
__global__ __launch_bounds__(256) void k_prep_w(const float* __restrict__ W_lin,
                                                const float* __restrict__ W1s,
                                                unsigned short* __restrict__ Wlt,
                                                unsigned short* __restrict__ Wt) {
    int idx = blockIdx.x * 256 + threadIdx.x;
    if (idx < 128 * 256) {
        int c = idx >> 8, k = idx & 255;
        Wlt[idx] = f2bf(W_lin[k * 128 + c]);
    } else {
        int j = idx - 128 * 256;
        if (j < 5 * 128 * 128) {
            int l = j >> 14;
            int rem = j & 16383;
            int c = rem >> 7, k = rem & 127;
            float bet = logf(0.5f / (float)(l + 1) + 1.0f);
            float v = bet * W1s[l * 16384 + k * 128 + c];
            if (c == k) v += 1.0f - bet;
            Wt[j] = f2bf(v);
        }
    }
}

// ---------------- bf16 MFMA GEMM: out[r][c] = sum_k A[r][k]*Bt[c][k] ----------------
// MODE 0: store bf16
// MODE 1: store bf16 + BN column sum/sumsq atomics
// MODE 2: store f32
template <int K, int MODE>
__global__ __launch_bounds__(256) void k_mgemm(const unsigned short* __restrict__ A,
                                               const unsigned short* __restrict__ Bt,
                                               unsigned short* __restrict__ outb,
                                               float* __restrict__ outf,
                                               float* __restrict__ bn_s, float* __restrict__ bn_q,
                                               int M) {
    __shared__ short lds[2 * 128 * 136];
    short* As = lds;
    short* Bs = lds + 128 * 136;

    int t = threadIdx.x;
    int lane = t & 63;
    int wave = t >> 6;
    int wr = wave >> 1, wc = wave & 1;
    int row0 = blockIdx.x * 128;

    f32x4 acc[4][4];
#pragma unroll
    for (int m = 0; m < 4; ++m)
#pragma unroll
        for (int n = 0; n < 4; ++n) acc[m][n] = (f32x4){0.f, 0.f, 0.f, 0.f};

    int sr = t >> 1;      // staged row (0..127)
    int sh = t & 1;       // half (64 elems each)

    for (int k0 = 0; k0 < K; k0 += 128) {
        // stage A chunk [128][128]
        {
            int gr = row0 + sr;
            uint4 zero = {0, 0, 0, 0};
            const uint4* gp = (const uint4*)(A + (size_t)gr * K + k0 + sh * 64);
#pragma unroll
            for (int u = 0; u < 8; ++u) {
                uint4 v = (gr < M) ? gp[u] : zero;
                *(uint4*)(As + sr * 136 + sh * 64 + u * 8) = v;
            }
        }
        // stage Bt chunk [128][128]
        {
            const uint4* gp = (const uint4*)(Bt + (size_t)sr * K + k0 + sh * 64);
#pragma unroll
            for (int u = 0; u < 8; ++u) {
                *(uint4*)(Bs + sr * 136 + sh * 64 + u * 8) = gp[u];
            }
        }
        __syncthreads();

#pragma unroll
        for (int ks = 0; ks < 4; ++ks) {
            bf16x8 af[4], bfr[4];
#pragma unroll
            for (int m = 0; m < 4; ++m)
                af[m] = *(const bf16x8*)(As + (wr * 64 + m * 16 + (lane & 15)) * 136 + ks * 32 + (lane >> 4) * 8);
#pragma unroll
            for (int n = 0; n < 4; ++n)
                bfr[n] = *(const bf16x8*)(Bs + (wc * 64 + n * 16 + (lane & 15)) * 136 + ks * 32 + (lane >> 4) * 8);
#pragma unroll
            for (int m = 0; m < 4; ++m)
#pragma unroll
                for (int n = 0; n < 4; ++n)
                    acc[m][n] = __builtin_amdgcn_mfma_f32_16x16x32_bf16(af[m], bfr[n], acc[m][n], 0, 0, 0);
        }
        __syncthreads();
    }

    if (MODE == 1) {
        float sum[4] = {0.f, 0.f, 0.f, 0.f}, sq[4] = {0.f, 0.f, 0.f, 0.f};
#pragma unroll
        for (int n = 0; n < 4; ++n)
#pragma unroll
            for (int m = 0; m < 4; ++m)
#pragma unroll
                for (int r = 0; r < 4; ++r) {
                    float v = acc[m][n][r];
                    sum[n] += v;
                    sq[n] += v * v;
                }
#pragma unroll
        for (int n = 0; n < 4; ++n) {
            sum[n] += __shfl_xor(sum[n], 16);
            sum[n] += __shfl_xor(sum[n], 32);
            sq[n] += __shfl_xor(sq[n], 16);
            sq[n] += __shfl_xor(sq[n], 32);
        }
        if (lane < 16) {
#pragma unroll
            for (int n = 0; n < 4; ++n) {
                int col = wc * 64 + n * 16 + lane;
                atomicAdd(&bn_s[col], sum[n]);
                atomicAdd(&bn_q[col], sq[n]);
            }
        }
    }

    // transpose-store via LDS
    if (MODE == 2) {
        float* Zf = (float*)lds;  // [128][132]
#pragma unroll
        for (int m = 0; m < 4; ++m)
#pragma unroll
            for (int n = 0; n < 4; ++n)
#pragma unroll
                for (int r = 0; r < 4; ++r) {
                    int rl = wr * 64 + m * 16 + (lane >> 4) * 4 + r;
                    int cl = wc * 64 + n * 16 + (lane & 15);
                    Zf[rl * 132 + cl] = acc[m][n][r];
                }
        __syncthreads();
        int gr = row0 + sr;
        if (gr < M) {
#pragma unroll
            for (int u = 0; u < 16; ++u)
                *(float4*)(outf + (size_t)gr * 128 + sh * 64 + u * 4) = *(float4*)(Zf + sr * 132 + sh * 64 + u * 4);
        }
    } else {
        short* Z = lds;  // [128][136] bf16
#pragma unroll
        for (int m = 0; m < 4; ++m)
#pragma unroll
            for (int n = 0; n < 4; ++n)
#pragma unroll
                for (int r = 0; r < 4; ++r) {
                    int rl = wr * 64 + m * 16 + (lane >> 4) * 4 + r;
                    int cl = wc * 64 + n * 16 + (lane & 15);
                    Z[rl * 136 + cl] = (short)f2bf(acc[m][n][r]);
                }
        __syncthreads();
        int gr = row0 + sr;
        if (gr < M) {
#pragma unroll
            for (int u = 0; u < 8; ++u)
                *(uint4*)(outb + (size_t)gr * 128 + sh * 64 + u * 8) = *(uint4*)(Z + sr * 136 + sh * 64 + u * 8);
        }
    }
}

// ---------------- GCNConv aggregation (bf16 rows, weighted, self-loop, +bias) ----------------
__global__ __launch_bounds__(256) void k_agg_gcn(const unsigned int* __restrict__ xwb,
                                                 const float* __restrict__ dinv,
                                                 const int* __restrict__ rp, const int* __restrict__ cs,
                                                 const float* __restrict__ b_lin,
                                                 unsigned int* __restrict__ x0b, int n) {
    int wid = (blockIdx.x * 256 + threadIdx.x) >> 6;
    int lane = threadIdx.x & 63;
    if (wid >= n) return;
    float dn = dinv[wid];
    int start = rp[wid], end = rp[wid + 1];
    float ax = 0.f, ay = 0.f;
    int j = start;
    for (; j + 1 < end; j += 2) {
        int s0 = cs[j], s1 = cs[j + 1];
        float w0 = dinv[s0] * dn, w1 = dinv[s1] * dn;
        unsigned int v0 = xwb[(size_t)s0 * 64 + lane];
        unsigned int v1 = xwb[(size_t)s1 * 64 + lane];
        ax = fmaf(w0, bf2f((unsigned short)v0), ax);
        ay = fmaf(w0, bf2f((unsigned short)(v0 >> 16)), ay);
        ax = fmaf(w1, bf2f((unsigned short)v1), ax);
        ay = fmaf(w1, bf2f((unsigned short)(v1 >> 16)), ay);
    }
    if (j < end) {
        int s0 = cs[j];
        float w0 = dinv[s0] * dn;
        unsigned int v0 = xwb[(size_t)s0 * 64 + lane];
        ax = fmaf(w0, bf2f((unsigned short)v0), ax);
        ay = fmaf(w0, bf2f((unsigned short)(v0 >> 16)), ay);
    }
    unsigned int vs = xwb[(size_t)wid * 64 + lane];
    float w2 = dn * dn;
    ax = fmaf(w2, bf2f((unsigned short)vs), ax);
    ay = fmaf(w2, bf2f((unsigned short)(vs >> 16)), ay);
    float2 bb = ((const float2*)b_lin)[lane];
    ax += bb.x;
    ay += bb.y;
    x0b[(size_t)wid * 64 + lane] = (unsigned int)f2bf(ax) | ((unsigned int)f2bf(ay) << 16);
}

// ---------------- GCN2 aggregation: h = 0.9*sum_j f(z[src]) + 0.1*x0 ----------------
template <int BN>
__global__ __launch_bounds__(256) void k_agg2(const unsigned int* __restrict__ zb,
                                              const unsigned int* __restrict__ x0b,
                                              const int* __restrict__ rp, const int* __restrict__ cs,
                                              const float* __restrict__ st,
                                              unsigned int* __restrict__ hb, int n) {
    int wid = (blockIdx.x * 256 + threadIdx.x) >> 6;
    int lane = threadIdx.x & 63;
    if (wid >= n) return;
    float2 sc = {0.f, 0.f}, tc = {0.f, 0.f};
    if (BN) {
        sc = ((const float2*)st)[lane];
        tc = ((const float2*)st)[64 + lane];
    }
    int start = rp[wid], end = rp[wid + 1];
    float ax = 0.f, ay = 0.f;
    int j = start;
    for (; j + 1 < end; j += 2) {
        unsigned int v0 = zb[(size_t)cs[j] * 64 + lane];
        unsigned int v1 = zb[(size_t)cs[j + 1] * 64 + lane];
        float f0x = bf2f((unsigned short)v0), f0y = bf2f((unsigned short)(v0 >> 16));
        float f1x = bf2f((unsigned short)v1), f1y = bf2f((unsigned short)(v1 >> 16));
        if (BN) {
            f0x = fmaxf(fmaf(sc.x, f0x, tc.x), 0.f);
            f0y = fmaxf(fmaf(sc.y, f0y, tc.y), 0.f);
            f1x = fmaxf(fmaf(sc.x, f1x, tc.x), 0.f);
            f1y = fmaxf(fmaf(sc.y, f1y, tc.y), 0.f);
        }
        ax += f0x + f1x;
        ay += f0y + f1y;
    }
    if (j < end) {
        unsigned int v0 = zb[(size_t)cs[j] * 64 + lane];
        float f0x = bf2f((unsigned short)v0), f0y = bf2f((unsigned short)(v0 >> 16));
        if (BN) {
            f0x = fmaxf(fmaf(sc.x, f0x, tc.x), 0.f);
            f0y = fmaxf(fmaf(sc.y, f0y, tc.y), 0.f);
        }
        ax += f0x;
        ay += f0y;
    }
    unsigned int xv = x0b[(size_t)wid * 64 + lane];
    float x0x = bf2f((unsigned short)xv), x0y = bf2f((unsigned short)(xv >> 16));
    float ox = fmaf(ALPHA, x0x, (1.0f - ALPHA) * ax);
    float oy = fmaf(ALPHA, x0y, (1.0f - ALPHA) * ay);
    hb[(size_t)wid * 64 + lane] = (unsigned int)f2bf(ox) | ((unsigned int)f2bf(oy) << 16);
}

// ---------------- BN finalize ----------------
__global__ void k_bn_fin(const float* __restrict__ bn_s, const float* __restrict__ bn_q,
                         const float* __restrict__ gamma, const float* __restrict__ betap,
                         float* __restrict__ st, int n) {
    int c = threadIdx.x;
    float inv_n = 1.0f / (float)n;
    float mu = bn_s[c] * inv_n;
    float var = bn_q[c] * inv_n - mu * mu;
    var = fmaxf(var, 0.f);
    float s = gamma[c] * rsqrtf(var + EPS);
    st[c] = s;
    st[128 + c] = betap[c] - mu * s;
}

extern "C" void kernel_launch(void* const* d_in, const int* in_sizes, int n_in,
                              void* d_out, int out_size, void* d_ws, size_t ws_size,
                              hipStream_t stream) {
    const float* x = (const float*)d_in[0];
    const int* ei = (const int*)d_in[1];
    const float* W_lin = (const float*)d_in[2];
    const float* b_lin = (const float*)d_in[3];
    const float* W1s = (const float*)d_in[4];
    const float* gam = (const float*)d_in[5];
    const float* betp = (const float*)d_in[6];
    float* out = (float*)d_out;

    char* ws = (char*)d_ws;
    size_t off = 0;
    auto alloc = [&](size_t b) { size_t p = off; off = (off + b + 255) & ~(size_t)255; return p; };
    int* cnt = (int*)(ws + alloc((size_t)N_NODES * 4));
    int* rp = (int*)(ws + alloc((size_t)(N_NODES + 1) * 4));
    int* fill = (int*)(ws + alloc((size_t)N_NODES * 4));
    int* cs = (int*)(ws + alloc((size_t)N_EDGES * 4));
    float* dinv = (float*)(ws + alloc((size_t)N_NODES * 4));
    int* bsum = (int*)(ws + alloc(256 * 4));
    int* boff = (int*)(ws + alloc(256 * 4));
    unsigned short* xb = (unsigned short*)(ws + alloc((size_t)N_NODES * D_IN * 2));
    unsigned short* xwb = (unsigned short*)(ws + alloc((size_t)N_NODES * D_HID * 2));
    unsigned short* x0b = (unsigned short*)(ws + alloc((size_t)N_NODES * D_HID * 2));
    unsigned short* zb = (unsigned short*)(ws + alloc((size_t)N_NODES * D_HID * 2));
    unsigned short* hb = (unsigned short*)(ws + alloc((size_t)N_NODES * D_HID * 2));
    unsigned short* Wlt = (unsigned short*)(ws + alloc((size_t)128 * 256 * 2));
    unsigned short* Wt = (unsigned short*)(ws + alloc((size_t)5 * 128 * 128 * 2));
    float* bns = (float*)(ws + alloc(256 * 4));
    float* st = (float*)(ws + alloc(256 * 4));

    const int egrid = (N_EDGES + 255) / 256;
    const int nblk = (N_NODES + 255) / 256;  // 196
    const int ggrid = (N_NODES + 127) / 128; // 391
    const int agrid = (N_NODES + 3) / 4;     // 12500

    // CSR build
    hipMemsetAsync(cnt, 0, (size_t)N_NODES * 4, stream);
    k_count<<<egrid, 256, 0, stream>>>(ei + N_EDGES, cnt, N_EDGES);
    k_bsum<<<nblk, 256, 0, stream>>>(cnt, bsum, N_NODES);
    k_bscan<<<1, 256, 0, stream>>>(bsum, boff, rp, nblk, N_NODES);
    k_scan2<<<nblk, 256, 0, stream>>>(cnt, boff, rp, fill, dinv, N_NODES);
    k_fill<<<egrid, 256, 0, stream>>>(ei, ei + N_EDGES, fill, cs, N_EDGES);

    // prep
    k_cast_x<<<(N_NODES * D_IN / 4 + 255) / 256, 256, 0, stream>>>((const float4*)x, (ushort2*)xb,
                                                                   N_NODES * D_IN / 4);
    k_prep_w<<<(128 * 256 + 5 * 128 * 128 + 255) / 256, 256, 0, stream>>>(W_lin, W1s, Wlt, Wt);

    // GCNConv
    k_mgemm<D_IN, 0><<<ggrid, 256, 0, stream>>>(xb, Wlt, xwb, nullptr, nullptr, nullptr, N_NODES);
    k_agg_gcn<<<agrid, 256, 0, stream>>>((const unsigned int*)xwb, dinv, rp, cs, b_lin,
                                         (unsigned int*)x0b, N_NODES);

    // 5x GCN2Conv
    for (int i = 0; i < 5; ++i) {
        const unsigned short* zsrc = (i == 0) ? x0b : zb;
        if (i == 0)
            k_agg2<0><<<agrid, 256, 0, stream>>>((const unsigned int*)zsrc, (const unsigned int*)x0b,
                                                 rp, cs, nullptr, (unsigned int*)hb, N_NODES);
        else
            k_agg2<1><<<agrid, 256, 0, stream>>>((const unsigned int*)zsrc, (const unsigned int*)x0b,
                                                 rp, cs, st, (unsigned int*)hb, N_NODES);
        const unsigned short* W1 = Wt + (size_t)i * 128 * 128;
        if (i < 4) {
            hipMemsetAsync(bns, 0, 256 * 4, stream);
            k_mgemm<D_HID, 1><<<ggrid, 256, 0, stream>>>(hb, W1, zb, nullptr, bns, bns + 128, N_NODES);
            k_bn_fin<<<1, 128, 0, stream>>>(bns, bns + 128, gam + (size_t)i * 128,
                                            betp + (size_t)i * 128, st, N_NODES);
        } else {
            k_mgemm<D_HID, 2><<<ggrid, 256, 0, stream>>>(hb, W1, nullptr, out, nullptr, nullptr, N_NODES);
        }
    }
}

// Round 3
// 470.498 us; speedup vs baseline: 2.1292x; 1.2483x over previous
//
#include <hip/hip_runtime.h>
#include <math.h>

#define N_NODES 50000
#define N_EDGES 800000
#define D_IN 256
#define D_HID 128
#define ALPHA 0.1f
#define EPS 1e-5f

typedef __attribute__((ext_vector_type(8))) short bf16x8;
typedef __attribute__((ext_vector_type(4))) float f32x4;

static __device__ __forceinline__ float bf2f(unsigned short u) {
    return __uint_as_float(((unsigned int)u) << 16);
}
static __device__ __forceinline__ unsigned short f2bf(float f) {
    unsigned int x = __float_as_uint(f);
    return (unsigned short)((x + 0x7fffu + ((x >> 16) & 1u)) >> 16);
}
static __device__ __forceinline__ float blo(unsigned int v) {
    return __uint_as_float(v << 16);
}
static __device__ __forceinline__ float bhi(unsigned int v) {
    return __uint_as_float(v & 0xffff0000u);
}

// ---------------- CSR build ----------------
__global__ void k_count(const int* __restrict__ dst, int* __restrict__ cnt, int e) {
    int i = blockIdx.x * 256 + threadIdx.x;
    if (i < e) atomicAdd(&cnt[dst[i]], 1);
}

__global__ __launch_bounds__(256) void k_bsum(const int* __restrict__ cnt, int* __restrict__ bsum, int n) {
    __shared__ int sh[256];
    int t = threadIdx.x;
    int i = blockIdx.x * 256 + t;
    sh[t] = (i < n) ? cnt[i] : 0;
    __syncthreads();
    for (int ofs = 128; ofs > 0; ofs >>= 1) {
        if (t < ofs) sh[t] += sh[t + ofs];
        __syncthreads();
    }
    if (t == 0) bsum[blockIdx.x] = sh[0];
}

__global__ __launch_bounds__(256) void k_bscan(const int* __restrict__ bsum, int* __restrict__ boff,
                                               int* __restrict__ rp, int nblk, int n) {
    __shared__ int sh[256];
    int t = threadIdx.x;
    int v = (t < nblk) ? bsum[t] : 0;
    sh[t] = v;
    __syncthreads();
    for (int ofs = 1; ofs < 256; ofs <<= 1) {
        int y = (t >= ofs) ? sh[t - ofs] : 0;
        __syncthreads();
        sh[t] += y;
        __syncthreads();
    }
    if (t < nblk) boff[t] = sh[t] - v;
    if (t == 255) rp[n] = sh[255];
}

__global__ __launch_bounds__(256) void k_scan2(const int* __restrict__ cnt, const int* __restrict__ boff,
                                               int* __restrict__ rp, int* __restrict__ fill,
                                               float* __restrict__ dinv, int n) {
    __shared__ int sh[256];
    int t = threadIdx.x;
    int i = blockIdx.x * 256 + t;
    int v = (i < n) ? cnt[i] : 0;
    sh[t] = v;
    __syncthreads();
    for (int ofs = 1; ofs < 256; ofs <<= 1) {
        int y = (t >= ofs) ? sh[t - ofs] : 0;
        __syncthreads();
        sh[t] += y;
        __syncthreads();
    }
    if (i < n) {
        int ex = boff[blockIdx.x] + sh[t] - v;
        rp[i] = ex;
        fill[i] = ex;
        dinv[i] = rsqrtf((float)(v + 1));
    }
}

__global__ void k_fill(const int* __restrict__ src, const int* __restrict__ dst,
                       int* __restrict__ fill, int* __restrict__ cs, int e) {
    int i = blockIdx.x * 256 + threadIdx.x;
    if (i < e) {
        int d = dst[i];
        int p = atomicAdd(&fill[d], 1);
        cs[p] = src[i];
    }
}

// ---------------- prep: cast x to bf16 ----------------
__global__ __launch_bounds__(256) void k_cast_x(const float4* __restrict__ x, ushort2* __restrict__ xb,
                                                int n4) {
    int i = blockIdx.x * 256 + threadIdx.x;
    if (i < n4) {
        float4 v = x[i];
        ushort2 a;
        a.x = f2bf(v.x); a.y = f2bf(v.y);
        ushort2 b;
        b.x = f2bf(v.z); b.y = f2bf(v.w);
        ((ushort2*)xb)[i * 2] = a;
        ((ushort2*)xb)[i * 2 + 1] = b;
    }
}

// ---------------- prep weights ----------------
__global__ __launch_bounds__(256) void k_prep_w(const float* __restrict__ W_lin,
                                                const float* __restrict__ W1s,
                                                unsigned short* __restrict__ Wlt,
                                                unsigned short* __restrict__ Wt) {
    int idx = blockIdx.x * 256 + threadIdx.x;
    if (idx < 128 * 256) {
        int c = idx >> 8, k = idx & 255;
        Wlt[idx] = f2bf(W_lin[k * 128 + c]);
    } else {
        int j = idx - 128 * 256;
        if (j < 5 * 128 * 128) {
            int l = j >> 14;
            int rem = j & 16383;
            int c = rem >> 7, k = rem & 127;
            float bet = logf(0.5f / (float)(l + 1) + 1.0f);
            float v = bet * W1s[l * 16384 + k * 128 + c];
            if (c == k) v += 1.0f - bet;
            Wt[j] = f2bf(v);
        }
    }
}

// ---------------- first GEMM (K=256): out bf16 = A @ Bt^T ----------------
template <int K>
__global__ __launch_bounds__(256) void k_mgemm(const unsigned short* __restrict__ A,
                                               const unsigned short* __restrict__ Bt,
                                               unsigned short* __restrict__ outb, int M) {
    __shared__ short lds[2 * 128 * 136];
    short* As = lds;
    short* Bs = lds + 128 * 136;

    int t = threadIdx.x;
    int lane = t & 63;
    int wave = t >> 6;
    int wr = wave >> 1, wc = wave & 1;
    int row0 = blockIdx.x * 128;

    f32x4 acc[4][4];
#pragma unroll
    for (int m = 0; m < 4; ++m)
#pragma unroll
        for (int n = 0; n < 4; ++n) acc[m][n] = (f32x4){0.f, 0.f, 0.f, 0.f};

    int sr = t >> 1;
    int sh = t & 1;

    for (int k0 = 0; k0 < K; k0 += 128) {
        {
            int gr = row0 + sr;
            uint4 zero = {0, 0, 0, 0};
            const uint4* gp = (const uint4*)(A + (size_t)gr * K + k0 + sh * 64);
#pragma unroll
            for (int u = 0; u < 8; ++u) {
                uint4 v = (gr < M) ? gp[u] : zero;
                *(uint4*)(As + sr * 136 + sh * 64 + u * 8) = v;
            }
        }
        {
            const uint4* gp = (const uint4*)(Bt + (size_t)sr * K + k0 + sh * 64);
#pragma unroll
            for (int u = 0; u < 8; ++u) {
                *(uint4*)(Bs + sr * 136 + sh * 64 + u * 8) = gp[u];
            }
        }
        __syncthreads();

#pragma unroll
        for (int ks = 0; ks < 4; ++ks) {
            bf16x8 af[4], bfr[4];
#pragma unroll
            for (int m = 0; m < 4; ++m)
                af[m] = *(const bf16x8*)(As + (wr * 64 + m * 16 + (lane & 15)) * 136 + ks * 32 + (lane >> 4) * 8);
#pragma unroll
            for (int n = 0; n < 4; ++n)
                bfr[n] = *(const bf16x8*)(Bs + (wc * 64 + n * 16 + (lane & 15)) * 136 + ks * 32 + (lane >> 4) * 8);
#pragma unroll
            for (int m = 0; m < 4; ++m)
#pragma unroll
                for (int n = 0; n < 4; ++n)
                    acc[m][n] = __builtin_amdgcn_mfma_f32_16x16x32_bf16(af[m], bfr[n], acc[m][n], 0, 0, 0);
        }
        __syncthreads();
    }

    short* Z = lds;
#pragma unroll
    for (int m = 0; m < 4; ++m)
#pragma unroll
        for (int n = 0; n < 4; ++n)
#pragma unroll
            for (int r = 0; r < 4; ++r) {
                int rl = wr * 64 + m * 16 + (lane >> 4) * 4 + r;
                int cl = wc * 64 + n * 16 + (lane & 15);
                Z[rl * 136 + cl] = (short)f2bf(acc[m][n][r]);
            }
    __syncthreads();
    int gr = row0 + sr;
    if (gr < M) {
#pragma unroll
        for (int u = 0; u < 8; ++u)
            *(uint4*)(outb + (size_t)gr * 128 + sh * 64 + u * 8) = *(uint4*)(Z + sr * 136 + sh * 64 + u * 8);
    }
}

// ---------------- layer GEMM (K=128): B in registers ----------------
// MODE 1: bf16 out + BN stats; MODE 2: f32 out
template <int MODE>
__global__ __launch_bounds__(256) void k_lgemm(const unsigned short* __restrict__ A,
                                               const unsigned short* __restrict__ Bt,
                                               unsigned short* __restrict__ outb,
                                               float* __restrict__ outf,
                                               float* __restrict__ bn_s, float* __restrict__ bn_q,
                                               int M) {
    __shared__ short As[128 * 136];
    int t = threadIdx.x;
    int lane = t & 63;
    int wave = t >> 6;
    int wr = wave >> 1, wc = wave & 1;
    int row0 = blockIdx.x * 128;

    // B fragments in registers (W' is 32 KB, L2-hot)
    bf16x8 bfr[4][4];  // [ks][n]
#pragma unroll
    for (int ks = 0; ks < 4; ++ks)
#pragma unroll
        for (int n = 0; n < 4; ++n)
            bfr[ks][n] = *(const bf16x8*)(Bt + (size_t)(wc * 64 + n * 16 + (lane & 15)) * 128 + ks * 32 + (lane >> 4) * 8);

    // stage A tile [128][128]
    int sr = t >> 1, sh = t & 1;
    {
        int gr = row0 + sr;
        uint4 zero = {0, 0, 0, 0};
        const uint4* gp = (const uint4*)(A + (size_t)gr * 128 + sh * 64);
#pragma unroll
        for (int u = 0; u < 8; ++u) {
            uint4 v = (gr < M) ? gp[u] : zero;
            *(uint4*)(As + sr * 136 + sh * 64 + u * 8) = v;
        }
    }
    __syncthreads();

    f32x4 acc[4][4];
#pragma unroll
    for (int m = 0; m < 4; ++m)
#pragma unroll
        for (int n = 0; n < 4; ++n) acc[m][n] = (f32x4){0.f, 0.f, 0.f, 0.f};

#pragma unroll
    for (int ks = 0; ks < 4; ++ks) {
        bf16x8 af[4];
#pragma unroll
        for (int m = 0; m < 4; ++m)
            af[m] = *(const bf16x8*)(As + (wr * 64 + m * 16 + (lane & 15)) * 136 + ks * 32 + (lane >> 4) * 8);
#pragma unroll
        for (int m = 0; m < 4; ++m)
#pragma unroll
            for (int n = 0; n < 4; ++n)
                acc[m][n] = __builtin_amdgcn_mfma_f32_16x16x32_bf16(af[m], bfr[ks][n], acc[m][n], 0, 0, 0);
    }

    if (MODE == 1) {
        float sum[4] = {0.f, 0.f, 0.f, 0.f}, sq[4] = {0.f, 0.f, 0.f, 0.f};
#pragma unroll
        for (int n = 0; n < 4; ++n)
#pragma unroll
            for (int m = 0; m < 4; ++m)
#pragma unroll
                for (int r = 0; r < 4; ++r) {
                    float v = acc[m][n][r];
                    sum[n] += v;
                    sq[n] += v * v;
                }
#pragma unroll
        for (int n = 0; n < 4; ++n) {
            sum[n] += __shfl_xor(sum[n], 16);
            sum[n] += __shfl_xor(sum[n], 32);
            sq[n] += __shfl_xor(sq[n], 16);
            sq[n] += __shfl_xor(sq[n], 32);
        }
        if (lane < 16) {
#pragma unroll
            for (int n = 0; n < 4; ++n) {
                int col = wc * 64 + n * 16 + lane;
                atomicAdd(&bn_s[col], sum[n]);
                atomicAdd(&bn_q[col], sq[n]);
            }
        }
    }

    if (MODE == 2) {
        // direct f32 stores (64B-contiguous per 16-lane group)
#pragma unroll
        for (int m = 0; m < 4; ++m)
#pragma unroll
            for (int n = 0; n < 4; ++n)
#pragma unroll
                for (int r = 0; r < 4; ++r) {
                    int gr = row0 + wr * 64 + m * 16 + (lane >> 4) * 4 + r;
                    int cl = wc * 64 + n * 16 + (lane & 15);
                    if (gr < M) outf[(size_t)gr * 128 + cl] = acc[m][n][r];
                }
    } else {
        __syncthreads();  // all MFMA reads of As done before overwrite
        short* Z = As;
#pragma unroll
        for (int m = 0; m < 4; ++m)
#pragma unroll
            for (int n = 0; n < 4; ++n)
#pragma unroll
                for (int r = 0; r < 4; ++r) {
                    int rl = wr * 64 + m * 16 + (lane >> 4) * 4 + r;
                    int cl = wc * 64 + n * 16 + (lane & 15);
                    Z[rl * 136 + cl] = (short)f2bf(acc[m][n][r]);
                }
        __syncthreads();
        int gr = row0 + sr;
        if (gr < M) {
#pragma unroll
            for (int u = 0; u < 8; ++u)
                *(uint4*)(outb + (size_t)gr * 128 + sh * 64 + u * 8) = *(uint4*)(Z + sr * 136 + sh * 64 + u * 8);
        }
    }
}

// ---------------- aggregation: one wave per node, shfl-broadcast indices ----------------
// MODE 0: GCNConv (weighted by dinv[s]*dinv[d], self-loop, +bias), src=xwb -> x0b
// MODE 1: GCN2 plain sum                                src=zb (=x0b layer0) -> hb
// MODE 2: GCN2 with fused BN+ReLU on sources            src=zb -> hb
template <int MODE>
__global__ __launch_bounds__(256) void k_agg(const unsigned int* __restrict__ src,
                                             const unsigned int* __restrict__ x0b,
                                             const int* __restrict__ rp, const int* __restrict__ cs,
                                             const float* __restrict__ dinv,
                                             const float* __restrict__ b_lin,
                                             const float* __restrict__ st,
                                             unsigned int* __restrict__ dst, int n) {
    int wid = (blockIdx.x * 256 + threadIdx.x) >> 6;
    int lane = threadIdx.x & 63;
    if (wid >= n) return;

    int start = __builtin_amdgcn_readfirstlane(rp[wid]);
    int end = __builtin_amdgcn_readfirstlane(rp[wid + 1]);

    float2 sc = {0.f, 0.f}, tc = {0.f, 0.f};
    if (MODE == 2) {
        sc = ((const float2*)st)[lane];
        tc = ((const float2*)st)[64 + lane];
    }
    float dn = 0.f;
    if (MODE == 0) dn = dinv[wid];

    float ax = 0.f, ay = 0.f;

    for (int base = start; base < end; base += 64) {
        int cnt = end - base;
        if (cnt > 64) cnt = 64;
        int myi = cs[base + ((lane < cnt) ? lane : 0)];
        float myw = 0.f;
        if (MODE == 0) myw = dinv[myi];

        int j = 0;
        for (; j + 3 < cnt; j += 4) {
            int s0 = __shfl(myi, j);
            int s1 = __shfl(myi, j + 1);
            int s2 = __shfl(myi, j + 2);
            int s3 = __shfl(myi, j + 3);
            unsigned int v0 = src[(size_t)s0 * 64 + lane];
            unsigned int v1 = src[(size_t)s1 * 64 + lane];
            unsigned int v2 = src[(size_t)s2 * 64 + lane];
            unsigned int v3 = src[(size_t)s3 * 64 + lane];
            if (MODE == 0) {
                float w0 = __shfl(myw, j) * dn;
                float w1 = __shfl(myw, j + 1) * dn;
                float w2 = __shfl(myw, j + 2) * dn;
                float w3 = __shfl(myw, j + 3) * dn;
                ax = fmaf(w0, blo(v0), ax); ay = fmaf(w0, bhi(v0), ay);
                ax = fmaf(w1, blo(v1), ax); ay = fmaf(w1, bhi(v1), ay);
                ax = fmaf(w2, blo(v2), ax); ay = fmaf(w2, bhi(v2), ay);
                ax = fmaf(w3, blo(v3), ax); ay = fmaf(w3, bhi(v3), ay);
            } else if (MODE == 1) {
                ax += blo(v0) + blo(v1) + blo(v2) + blo(v3);
                ay += bhi(v0) + bhi(v1) + bhi(v2) + bhi(v3);
            } else {
                ax += fmaxf(fmaf(sc.x, blo(v0), tc.x), 0.f) + fmaxf(fmaf(sc.x, blo(v1), tc.x), 0.f) +
                      fmaxf(fmaf(sc.x, blo(v2), tc.x), 0.f) + fmaxf(fmaf(sc.x, blo(v3), tc.x), 0.f);
                ay += fmaxf(fmaf(sc.y, bhi(v0), tc.y), 0.f) + fmaxf(fmaf(sc.y, bhi(v1), tc.y), 0.f) +
                      fmaxf(fmaf(sc.y, bhi(v2), tc.y), 0.f) + fmaxf(fmaf(sc.y, bhi(v3), tc.y), 0.f);
            }
        }
        for (; j < cnt; ++j) {
            int s0 = __shfl(myi, j);
            unsigned int v0 = src[(size_t)s0 * 64 + lane];
            if (MODE == 0) {
                float w0 = __shfl(myw, j) * dn;
                ax = fmaf(w0, blo(v0), ax);
                ay = fmaf(w0, bhi(v0), ay);
            } else if (MODE == 1) {
                ax += blo(v0);
                ay += bhi(v0);
            } else {
                ax += fmaxf(fmaf(sc.x, blo(v0), tc.x), 0.f);
                ay += fmaxf(fmaf(sc.y, bhi(v0), tc.y), 0.f);
            }
        }
    }

    if (MODE == 0) {
        unsigned int vs = src[(size_t)wid * 64 + lane];
        float w2 = dn * dn;
        ax = fmaf(w2, blo(vs), ax);
        ay = fmaf(w2, bhi(vs), ay);
        float2 bb = ((const float2*)b_lin)[lane];
        ax += bb.x;
        ay += bb.y;
    } else {
        unsigned int xv = x0b[(size_t)wid * 64 + lane];
        ax = fmaf(ALPHA, blo(xv), (1.0f - ALPHA) * ax);
        ay = fmaf(ALPHA, bhi(xv), (1.0f - ALPHA) * ay);
    }
    dst[(size_t)wid * 64 + lane] = (unsigned int)f2bf(ax) | ((unsigned int)f2bf(ay) << 16);
}

// ---------------- BN finalize ----------------
__global__ void k_bn_fin(const float* __restrict__ bn_s, const float* __restrict__ bn_q,
                         const float* __restrict__ gamma, const float* __restrict__ betap,
                         float* __restrict__ st, int n) {
    int c = threadIdx.x;
    float inv_n = 1.0f / (float)n;
    float mu = bn_s[c] * inv_n;
    float var = bn_q[c] * inv_n - mu * mu;
    var = fmaxf(var, 0.f);
    float s = gamma[c] * rsqrtf(var + EPS);
    st[c] = s;
    st[128 + c] = betap[c] - mu * s;
}

extern "C" void kernel_launch(void* const* d_in, const int* in_sizes, int n_in,
                              void* d_out, int out_size, void* d_ws, size_t ws_size,
                              hipStream_t stream) {
    const float* x = (const float*)d_in[0];
    const int* ei = (const int*)d_in[1];
    const float* W_lin = (const float*)d_in[2];
    const float* b_lin = (const float*)d_in[3];
    const float* W1s = (const float*)d_in[4];
    const float* gam = (const float*)d_in[5];
    const float* betp = (const float*)d_in[6];
    float* out = (float*)d_out;

    char* ws = (char*)d_ws;
    size_t off = 0;
    auto alloc = [&](size_t b) { size_t p = off; off = (off + b + 255) & ~(size_t)255; return p; };
    int* cnt = (int*)(ws + alloc((size_t)N_NODES * 4));
    int* rp = (int*)(ws + alloc((size_t)(N_NODES + 1) * 4));
    int* fill = (int*)(ws + alloc((size_t)N_NODES * 4));
    int* cs = (int*)(ws + alloc((size_t)N_EDGES * 4));
    float* dinv = (float*)(ws + alloc((size_t)N_NODES * 4));
    int* bsum = (int*)(ws + alloc(256 * 4));
    int* boff = (int*)(ws + alloc(256 * 4));
    unsigned short* xb = (unsigned short*)(ws + alloc((size_t)N_NODES * D_IN * 2));
    unsigned short* xwb = (unsigned short*)(ws + alloc((size_t)N_NODES * D_HID * 2));
    unsigned short* x0b = (unsigned short*)(ws + alloc((size_t)N_NODES * D_HID * 2));
    unsigned short* zb = (unsigned short*)(ws + alloc((size_t)N_NODES * D_HID * 2));
    unsigned short* hb = (unsigned short*)(ws + alloc((size_t)N_NODES * D_HID * 2));
    unsigned short* Wlt = (unsigned short*)(ws + alloc((size_t)128 * 256 * 2));
    unsigned short* Wt = (unsigned short*)(ws + alloc((size_t)5 * 128 * 128 * 2));
    float* bns = (float*)(ws + alloc(256 * 4));
    float* st = (float*)(ws + alloc(256 * 4));

    const int egrid = (N_EDGES + 255) / 256;
    const int nblk = (N_NODES + 255) / 256;
    const int ggrid = (N_NODES + 127) / 128;
    const int agrid = (N_NODES + 3) / 4;

    hipMemsetAsync(cnt, 0, (size_t)N_NODES * 4, stream);
    k_count<<<egrid, 256, 0, stream>>>(ei + N_EDGES, cnt, N_EDGES);
    k_bsum<<<nblk, 256, 0, stream>>>(cnt, bsum, N_NODES);
    k_bscan<<<1, 256, 0, stream>>>(bsum, boff, rp, nblk, N_NODES);
    k_scan2<<<nblk, 256, 0, stream>>>(cnt, boff, rp, fill, dinv, N_NODES);
    k_fill<<<egrid, 256, 0, stream>>>(ei, ei + N_EDGES, fill, cs, N_EDGES);

    k_cast_x<<<(N_NODES * D_IN / 4 + 255) / 256, 256, 0, stream>>>((const float4*)x, (ushort2*)xb,
                                                                   N_NODES * D_IN / 4);
    k_prep_w<<<(128 * 256 + 5 * 128 * 128 + 255) / 256, 256, 0, stream>>>(W_lin, W1s, Wlt, Wt);

    // GCNConv
    k_mgemm<D_IN><<<ggrid, 256, 0, stream>>>(xb, Wlt, xwb, N_NODES);
    k_agg<0><<<agrid, 256, 0, stream>>>((const unsigned int*)xwb, nullptr, rp, cs, dinv, b_lin,
                                        nullptr, (unsigned int*)x0b, N_NODES);

    // 5x GCN2Conv
    for (int i = 0; i < 5; ++i) {
        const unsigned short* zsrc = (i == 0) ? x0b : zb;
        if (i == 0)
            k_agg<1><<<agrid, 256, 0, stream>>>((const unsigned int*)zsrc, (const unsigned int*)x0b,
                                                rp, cs, nullptr, nullptr, nullptr,
                                                (unsigned int*)hb, N_NODES);
        else
            k_agg<2><<<agrid, 256, 0, stream>>>((const unsigned int*)zsrc, (const unsigned int*)x0b,
                                                rp, cs, nullptr, nullptr, st,
                                                (unsigned int*)hb, N_NODES);
        const unsigned short* W1 = Wt + (size_t)i * 128 * 128;
        if (i < 4) {
            hipMemsetAsync(bns, 0, 256 * 4, stream);
            k_lgemm<1><<<ggrid, 256, 0, stream>>>(hb, W1, zb, nullptr, bns, bns + 128, N_NODES);
            k_bn_fin<<<1, 128, 0, stream>>>(bns, bns + 128, gam + (size_t)i * 128,
                                            betp + (size_t)i * 128, st, N_NODES);
        } else {
            k_lgemm<2><<<ggrid, 256, 0, stream>>>(hb, W1, nullptr, out, nullptr, nullptr, N_NODES);
        }
    }
}

// Round 5
// 407.654 us; speedup vs baseline: 2.4574x; 1.1542x over previous
//
#include <hip/hip_runtime.h>
#include <math.h>

#define N_NODES 50000
#define N_EDGES 800000
#define D_IN 256
#define D_HID 128
#define ALPHA 0.1f
#define EPS 1e-5f

#define NBUCK 391   // ceil(50000/128)
#define EPB 4096    // edges per histogram/scatter block
#define NBLK 196    // ceil(800000/4096)

typedef __attribute__((ext_vector_type(8))) short bf16x8;
typedef __attribute__((ext_vector_type(4))) float f32x4;

static __device__ __forceinline__ unsigned short f2bf(float f) {
    unsigned int x = __float_as_uint(f);
    return (unsigned short)((x + 0x7fffu + ((x >> 16) & 1u)) >> 16);
}
static __device__ __forceinline__ float blo(unsigned int v) {
    return __uint_as_float(v << 16);
}
static __device__ __forceinline__ float bhi(unsigned int v) {
    return __uint_as_float(v & 0xffff0000u);
}

// ---------------- CSR build: hierarchical counting sort ----------------
__global__ __launch_bounds__(256) void k_hist(const int* __restrict__ dst,
                                              int* __restrict__ hist, int e) {
    __shared__ int h[NBUCK];
    int t = threadIdx.x;
    for (int i = t; i < NBUCK; i += 256) h[i] = 0;
    __syncthreads();
    int base = blockIdx.x * EPB;
    int lim = e - base;
    if (lim > EPB) lim = EPB;
    for (int i = t; i < lim; i += 256) atomicAdd(&h[dst[base + i] >> 7], 1);
    __syncthreads();
    for (int i = t; i < NBUCK; i += 256) hist[blockIdx.x * NBUCK + i] = h[i];
}

// per-bucket exclusive scan over blocks -> offsT[b][blk], btot[b]
__global__ __launch_bounds__(256) void k_bkscan(const int* __restrict__ hist,
                                                int* __restrict__ offsT, int* __restrict__ btot) {
    __shared__ int sh[256];
    int b = blockIdx.x;
    int t = threadIdx.x;
    int v = (t < NBLK) ? hist[t * NBUCK + b] : 0;
    sh[t] = v;
    __syncthreads();
    for (int ofs = 1; ofs < 256; ofs <<= 1) {
        int y = (t >= ofs) ? sh[t - ofs] : 0;
        __syncthreads();
        sh[t] += y;
        __syncthreads();
    }
    if (t < NBLK) offsT[b * NBLK + t] = sh[t] - v;
    if (t == 255) btot[b] = sh[255];
}

// scan bucket totals -> bbase (exclusive); write rp[N]
__global__ __launch_bounds__(512) void k_bbase(const int* __restrict__ btot,
                                               int* __restrict__ bbase, int* __restrict__ rp) {
    __shared__ int sh[512];
    int t = threadIdx.x;
    int v = (t < NBUCK) ? btot[t] : 0;
    sh[t] = v;
    __syncthreads();
    for (int ofs = 1; ofs < 512; ofs <<= 1) {
        int y = (t >= ofs) ? sh[t - ofs] : 0;
        __syncthreads();
        sh[t] += y;
        __syncthreads();
    }
    if (t < NBUCK) bbase[t] = sh[t] - v;
    if (t == 0) rp[N_NODES] = N_EDGES;
}

__global__ __launch_bounds__(256) void k_scatter(const int* __restrict__ src,
                                                 const int* __restrict__ dst,
                                                 const int* __restrict__ offsT,
                                                 const int* __restrict__ bbase,
                                                 unsigned int* __restrict__ buck, int e) {
    __shared__ int h[NBUCK];
    int t = threadIdx.x;
    for (int i = t; i < NBUCK; i += 256) h[i] = 0;
    __syncthreads();
    int base = blockIdx.x * EPB;
    int lim = e - base;
    if (lim > EPB) lim = EPB;
    for (int i = t; i < lim; i += 256) {
        int d = dst[base + i];
        int s = src[base + i];
        int b = d >> 7;
        int lp = atomicAdd(&h[b], 1);
        int pos = bbase[b] + offsT[b * NBLK + blockIdx.x] + lp;
        buck[pos] = (unsigned int)s | ((unsigned int)(d & 127) << 16);
    }
}

// per-bucket CSR finalize: rp, dinv, cs (all coalesced; bucket region contiguous)
__global__ __launch_bounds__(256) void k_csr(const unsigned int* __restrict__ buck,
                                             const int* __restrict__ bbase,
                                             const int* __restrict__ btot,
                                             int* __restrict__ rp, float* __restrict__ dinv,
                                             int* __restrict__ cs) {
    __shared__ int dcnt[128];
    __shared__ int doff[128];
    int b = blockIdx.x;
    int t = threadIdx.x;
    if (t < 128) dcnt[t] = 0;
    __syncthreads();
    int base = bbase[b];
    int tot = btot[b];
    for (int i = t; i < tot; i += 256) {
        unsigned int v = buck[base + i];
        atomicAdd(&dcnt[(v >> 16) & 127], 1);
    }
    __syncthreads();
    if (t < 128) doff[t] = dcnt[t];
    __syncthreads();
    for (int ofs = 1; ofs < 128; ofs <<= 1) {
        int y = 0;
        if (t < 128 && t >= ofs) y = doff[t - ofs];
        __syncthreads();
        if (t < 128) doff[t] += y;
        __syncthreads();
    }
    int gd0 = b << 7;
    if (t < 128) {
        int ex = doff[t] - dcnt[t];
        if (gd0 + t < N_NODES) {
            rp[gd0 + t] = base + ex;
            dinv[gd0 + t] = rsqrtf((float)(dcnt[t] + 1));
        }
        dcnt[t] = ex;  // allocation cursor
    }
    __syncthreads();
    for (int i = t; i < tot; i += 256) {
        unsigned int v = buck[base + i];
        int p = atomicAdd(&dcnt[(v >> 16) & 127], 1);
        cs[base + p] = (int)(v & 0xffffu);
    }
}

// ---------------- prep: cast x to bf16 ----------------
__global__ __launch_bounds__(256) void k_cast_x(const float4* __restrict__ x, ushort2* __restrict__ xb,
                                                int n4) {
    int i = blockIdx.x * 256 + threadIdx.x;
    if (i < n4) {
        float4 v = x[i];
        ushort2 a;
        a.x = f2bf(v.x); a.y = f2bf(v.y);
        ushort2 b;
        b.x = f2bf(v.z); b.y = f2bf(v.w);
        ((ushort2*)xb)[i * 2] = a;
        ((ushort2*)xb)[i * 2 + 1] = b;
    }
}

// ---------------- prep weights ----------------
__global__ __launch_bounds__(256) void k_prep_w(const float* __restrict__ W_lin,
                                                const float* __restrict__ W1s,
                                                unsigned short* __restrict__ Wlt,
                                                unsigned short* __restrict__ Wt) {
    int idx = blockIdx.x * 256 + threadIdx.x;
    if (idx < 128 * 256) {
        int c = idx >> 8, k = idx & 255;
        Wlt[idx] = f2bf(W_lin[k * 128 + c]);
    } else {
        int j = idx - 128 * 256;
        if (j < 5 * 128 * 128) {
            int l = j >> 14;
            int rem = j & 16383;
            int c = rem >> 7, k = rem & 127;
            float bet = logf(0.5f / (float)(l + 1) + 1.0f);
            float v = bet * W1s[l * 16384 + k * 128 + c];
            if (c == k) v += 1.0f - bet;
            Wt[j] = f2bf(v);
        }
    }
}

// ---------------- first GEMM (K=256): out bf16 = A @ Bt^T ----------------
template <int K>
__global__ __launch_bounds__(256) void k_mgemm(const unsigned short* __restrict__ A,
                                               const unsigned short* __restrict__ Bt,
                                               unsigned short* __restrict__ outb, int M) {
    __shared__ short lds[2 * 128 * 136];
    short* As = lds;
    short* Bs = lds + 128 * 136;

    int t = threadIdx.x;
    int lane = t & 63;
    int wave = t >> 6;
    int wr = wave >> 1, wc = wave & 1;
    int row0 = blockIdx.x * 128;

    f32x4 acc[4][4];
#pragma unroll
    for (int m = 0; m < 4; ++m)
#pragma unroll
        for (int n = 0; n < 4; ++n) acc[m][n] = (f32x4){0.f, 0.f, 0.f, 0.f};

    int sr = t >> 1;
    int sh = t & 1;

    for (int k0 = 0; k0 < K; k0 += 128) {
        {
            int gr = row0 + sr;
            uint4 zero = {0, 0, 0, 0};
            const uint4* gp = (const uint4*)(A + (size_t)gr * K + k0 + sh * 64);
#pragma unroll
            for (int u = 0; u < 8; ++u) {
                uint4 v = (gr < M) ? gp[u] : zero;
                *(uint4*)(As + sr * 136 + sh * 64 + u * 8) = v;
            }
        }
        {
            const uint4* gp = (const uint4*)(Bt + (size_t)sr * K + k0 + sh * 64);
#pragma unroll
            for (int u = 0; u < 8; ++u) {
                *(uint4*)(Bs + sr * 136 + sh * 64 + u * 8) = gp[u];
            }
        }
        __syncthreads();

#pragma unroll
        for (int ks = 0; ks < 4; ++ks) {
            bf16x8 af[4], bfr[4];
#pragma unroll
            for (int m = 0; m < 4; ++m)
                af[m] = *(const bf16x8*)(As + (wr * 64 + m * 16 + (lane & 15)) * 136 + ks * 32 + (lane >> 4) * 8);
#pragma unroll
            for (int n = 0; n < 4; ++n)
                bfr[n] = *(const bf16x8*)(Bs + (wc * 64 + n * 16 + (lane & 15)) * 136 + ks * 32 + (lane >> 4) * 8);
#pragma unroll
            for (int m = 0; m < 4; ++m)
#pragma unroll
                for (int n = 0; n < 4; ++n)
                    acc[m][n] = __builtin_amdgcn_mfma_f32_16x16x32_bf16(af[m], bfr[n], acc[m][n], 0, 0, 0);
        }
        __syncthreads();
    }

    short* Z = lds;
#pragma unroll
    for (int m = 0; m < 4; ++m)
#pragma unroll
        for (int n = 0; n < 4; ++n)
#pragma unroll
            for (int r = 0; r < 4; ++r) {
                int rl = wr * 64 + m * 16 + (lane >> 4) * 4 + r;
                int cl = wc * 64 + n * 16 + (lane & 15);
                Z[rl * 136 + cl] = (short)f2bf(acc[m][n][r]);
            }
    __syncthreads();
    int gr = row0 + sr;
    if (gr < M) {
#pragma unroll
        for (int u = 0; u < 8; ++u)
            *(uint4*)(outb + (size_t)gr * 128 + sh * 64 + u * 8) = *(uint4*)(Z + sr * 136 + sh * 64 + u * 8);
    }
}

// ---------------- layer GEMM (K=128): B in registers ----------------
template <int MODE>
__global__ __launch_bounds__(256) void k_lgemm(const unsigned short* __restrict__ A,
                                               const unsigned short* __restrict__ Bt,
                                               unsigned short* __restrict__ outb,
                                               float* __restrict__ outf,
                                               float* __restrict__ bn_s, float* __restrict__ bn_q,
                                               int M) {
    __shared__ short As[128 * 136];
    int t = threadIdx.x;
    int lane = t & 63;
    int wave = t >> 6;
    int wr = wave >> 1, wc = wave & 1;
    int row0 = blockIdx.x * 128;

    bf16x8 bfr[4][4];
#pragma unroll
    for (int ks = 0; ks < 4; ++ks)
#pragma unroll
        for (int n = 0; n < 4; ++n)
            bfr[ks][n] = *(const bf16x8*)(Bt + (size_t)(wc * 64 + n * 16 + (lane & 15)) * 128 + ks * 32 + (lane >> 4) * 8);

    int sr = t >> 1, sh = t & 1;
    {
        int gr = row0 + sr;
        uint4 zero = {0, 0, 0, 0};
        const uint4* gp = (const uint4*)(A + (size_t)gr * 128 + sh * 64);
#pragma unroll
        for (int u = 0; u < 8; ++u) {
            uint4 v = (gr < M) ? gp[u] : zero;
            *(uint4*)(As + sr * 136 + sh * 64 + u * 8) = v;
        }
    }
    __syncthreads();

    f32x4 acc[4][4];
#pragma unroll
    for (int m = 0; m < 4; ++m)
#pragma unroll
        for (int n = 0; n < 4; ++n) acc[m][n] = (f32x4){0.f, 0.f, 0.f, 0.f};

#pragma unroll
    for (int ks = 0; ks < 4; ++ks) {
        bf16x8 af[4];
#pragma unroll
        for (int m = 0; m < 4; ++m)
            af[m] = *(const bf16x8*)(As + (wr * 64 + m * 16 + (lane & 15)) * 136 + ks * 32 + (lane >> 4) * 8);
#pragma unroll
        for (int m = 0; m < 4; ++m)
#pragma unroll
            for (int n = 0; n < 4; ++n)
                acc[m][n] = __builtin_amdgcn_mfma_f32_16x16x32_bf16(af[m], bfr[ks][n], acc[m][n], 0, 0, 0);
    }

    if (MODE == 1) {
        float sum[4] = {0.f, 0.f, 0.f, 0.f}, sq[4] = {0.f, 0.f, 0.f, 0.f};
#pragma unroll
        for (int n = 0; n < 4; ++n)
#pragma unroll
            for (int m = 0; m < 4; ++m)
#pragma unroll
                for (int r = 0; r < 4; ++r) {
                    float v = acc[m][n][r];
                    sum[n] += v;
                    sq[n] += v * v;
                }
#pragma unroll
        for (int n = 0; n < 4; ++n) {
            sum[n] += __shfl_xor(sum[n], 16);
            sum[n] += __shfl_xor(sum[n], 32);
            sq[n] += __shfl_xor(sq[n], 16);
            sq[n] += __shfl_xor(sq[n], 32);
        }
        if (lane < 16) {
#pragma unroll
            for (int n = 0; n < 4; ++n) {
                int col = wc * 64 + n * 16 + lane;
                atomicAdd(&bn_s[col], sum[n]);
                atomicAdd(&bn_q[col], sq[n]);
            }
        }
    }

    if (MODE == 2) {
#pragma unroll
        for (int m = 0; m < 4; ++m)
#pragma unroll
            for (int n = 0; n < 4; ++n)
#pragma unroll
                for (int r = 0; r < 4; ++r) {
                    int gr = row0 + wr * 64 + m * 16 + (lane >> 4) * 4 + r;
                    int cl = wc * 64 + n * 16 + (lane & 15);
                    if (gr < M) outf[(size_t)gr * 128 + cl] = acc[m][n][r];
                }
    } else {
        __syncthreads();
        short* Z = As;
#pragma unroll
        for (int m = 0; m < 4; ++m)
#pragma unroll
            for (int n = 0; n < 4; ++n)
#pragma unroll
                for (int r = 0; r < 4; ++r) {
                    int rl = wr * 64 + m * 16 + (lane >> 4) * 4 + r;
                    int cl = wc * 64 + n * 16 + (lane & 15);
                    Z[rl * 136 + cl] = (short)f2bf(acc[m][n][r]);
                }
        __syncthreads();
        int gr = row0 + sr;
        if (gr < M) {
#pragma unroll
            for (int u = 0; u < 8; ++u)
                *(uint4*)(outb + (size_t)gr * 128 + sh * 64 + u * 8) = *(uint4*)(Z + sr * 136 + sh * 64 + u * 8);
        }
    }
}

// ---------------- aggregation: one wave per node, shfl-broadcast, unroll 8 ----------------
// MODE 0: GCNConv; MODE 1: GCN2 plain; MODE 2: GCN2 + fused BN/ReLU
template <int MODE>
__global__ __launch_bounds__(256) void k_agg(const unsigned int* __restrict__ src,
                                             const unsigned int* __restrict__ x0b,
                                             const int* __restrict__ rp, const int* __restrict__ cs,
                                             const float* __restrict__ dinv,
                                             const float* __restrict__ b_lin,
                                             const float* __restrict__ st,
                                             unsigned int* __restrict__ dst,
                                             float* __restrict__ bns, int n) {
    if (blockIdx.x == 0) bns[threadIdx.x] = 0.f;  // zero BN stats for the following GEMM

    int wid = (blockIdx.x * 256 + threadIdx.x) >> 6;
    int lane = threadIdx.x & 63;
    if (wid >= n) return;

    int start = __builtin_amdgcn_readfirstlane(rp[wid]);
    int end = __builtin_amdgcn_readfirstlane(rp[wid + 1]);

    float2 sc = {0.f, 0.f}, tc = {0.f, 0.f};
    if (MODE == 2) {
        sc = ((const float2*)st)[lane];
        tc = ((const float2*)st)[64 + lane];
    }
    float dn = 0.f;
    if (MODE == 0) dn = dinv[wid];

    float ax = 0.f, ay = 0.f;

    for (int base = start; base < end; base += 64) {
        int cnt = end - base;
        if (cnt > 64) cnt = 64;
        int myi = cs[base + ((lane < cnt) ? lane : 0)];
        float myw = 0.f;
        if (MODE == 0) myw = dinv[myi];

        int j = 0;
        for (; j + 7 < cnt; j += 8) {
            int s0 = __shfl(myi, j), s1 = __shfl(myi, j + 1);
            int s2 = __shfl(myi, j + 2), s3 = __shfl(myi, j + 3);
            int s4 = __shfl(myi, j + 4), s5 = __shfl(myi, j + 5);
            int s6 = __shfl(myi, j + 6), s7 = __shfl(myi, j + 7);
            unsigned int v0 = src[(size_t)s0 * 64 + lane];
            unsigned int v1 = src[(size_t)s1 * 64 + lane];
            unsigned int v2 = src[(size_t)s2 * 64 + lane];
            unsigned int v3 = src[(size_t)s3 * 64 + lane];
            unsigned int v4 = src[(size_t)s4 * 64 + lane];
            unsigned int v5 = src[(size_t)s5 * 64 + lane];
            unsigned int v6 = src[(size_t)s6 * 64 + lane];
            unsigned int v7 = src[(size_t)s7 * 64 + lane];
            if (MODE == 0) {
                float w0 = __shfl(myw, j) * dn, w1 = __shfl(myw, j + 1) * dn;
                float w2 = __shfl(myw, j + 2) * dn, w3 = __shfl(myw, j + 3) * dn;
                float w4 = __shfl(myw, j + 4) * dn, w5 = __shfl(myw, j + 5) * dn;
                float w6 = __shfl(myw, j + 6) * dn, w7 = __shfl(myw, j + 7) * dn;
                ax = fmaf(w0, blo(v0), ax); ay = fmaf(w0, bhi(v0), ay);
                ax = fmaf(w1, blo(v1), ax); ay = fmaf(w1, bhi(v1), ay);
                ax = fmaf(w2, blo(v2), ax); ay = fmaf(w2, bhi(v2), ay);
                ax = fmaf(w3, blo(v3), ax); ay = fmaf(w3, bhi(v3), ay);
                ax = fmaf(w4, blo(v4), ax); ay = fmaf(w4, bhi(v4), ay);
                ax = fmaf(w5, blo(v5), ax); ay = fmaf(w5, bhi(v5), ay);
                ax = fmaf(w6, blo(v6), ax); ay = fmaf(w6, bhi(v6), ay);
                ax = fmaf(w7, blo(v7), ax); ay = fmaf(w7, bhi(v7), ay);
            } else if (MODE == 1) {
                ax += blo(v0) + blo(v1) + blo(v2) + blo(v3) + blo(v4) + blo(v5) + blo(v6) + blo(v7);
                ay += bhi(v0) + bhi(v1) + bhi(v2) + bhi(v3) + bhi(v4) + bhi(v5) + bhi(v6) + bhi(v7);
            } else {
                ax += fmaxf(fmaf(sc.x, blo(v0), tc.x), 0.f) + fmaxf(fmaf(sc.x, blo(v1), tc.x), 0.f) +
                      fmaxf(fmaf(sc.x, blo(v2), tc.x), 0.f) + fmaxf(fmaf(sc.x, blo(v3), tc.x), 0.f) +
                      fmaxf(fmaf(sc.x, blo(v4), tc.x), 0.f) + fmaxf(fmaf(sc.x, blo(v5), tc.x), 0.f) +
                      fmaxf(fmaf(sc.x, blo(v6), tc.x), 0.f) + fmaxf(fmaf(sc.x, blo(v7), tc.x), 0.f);
                ay += fmaxf(fmaf(sc.y, bhi(v0), tc.y), 0.f) + fmaxf(fmaf(sc.y, bhi(v1), tc.y), 0.f) +
                      fmaxf(fmaf(sc.y, bhi(v2), tc.y), 0.f) + fmaxf(fmaf(sc.y, bhi(v3), tc.y), 0.f) +
                      fmaxf(fmaf(sc.y, bhi(v4), tc.y), 0.f) + fmaxf(fmaf(sc.y, bhi(v5), tc.y), 0.f) +
                      fmaxf(fmaf(sc.y, bhi(v6), tc.y), 0.f) + fmaxf(fmaf(sc.y, bhi(v7), tc.y), 0.f);
            }
        }
        for (; j < cnt; ++j) {
            int s0 = __shfl(myi, j);
            unsigned int v0 = src[(size_t)s0 * 64 + lane];
            if (MODE == 0) {
                float w0 = __shfl(myw, j) * dn;
                ax = fmaf(w0, blo(v0), ax);
                ay = fmaf(w0, bhi(v0), ay);
            } else if (MODE == 1) {
                ax += blo(v0);
                ay += bhi(v0);
            } else {
                ax += fmaxf(fmaf(sc.x, blo(v0), tc.x), 0.f);
                ay += fmaxf(fmaf(sc.y, bhi(v0), tc.y), 0.f);
            }
        }
    }

    if (MODE == 0) {
        unsigned int vs = src[(size_t)wid * 64 + lane];
        float w2 = dn * dn;
        ax = fmaf(w2, blo(vs), ax);
        ay = fmaf(w2, bhi(vs), ay);
        float2 bb = ((const float2*)b_lin)[lane];
        ax += bb.x;
        ay += bb.y;
    } else {
        unsigned int xv = x0b[(size_t)wid * 64 + lane];
        ax = fmaf(ALPHA, blo(xv), (1.0f - ALPHA) * ax);
        ay = fmaf(ALPHA, bhi(xv), (1.0f - ALPHA) * ay);
    }
    dst[(size_t)wid * 64 + lane] = (unsigned int)f2bf(ax) | ((unsigned int)f2bf(ay) << 16);
}

// ---------------- BN finalize ----------------
__global__ void k_bn_fin(const float* __restrict__ bn_s, const float* __restrict__ bn_q,
                         const float* __restrict__ gamma, const float* __restrict__ betap,
                         float* __restrict__ st, int n) {
    int c = threadIdx.x;
    float inv_n = 1.0f / (float)n;
    float mu = bn_s[c] * inv_n;
    float var = bn_q[c] * inv_n - mu * mu;
    var = fmaxf(var, 0.f);
    float s = gamma[c] * rsqrtf(var + EPS);
    st[c] = s;
    st[128 + c] = betap[c] - mu * s;
}

extern "C" void kernel_launch(void* const* d_in, const int* in_sizes, int n_in,
                              void* d_out, int out_size, void* d_ws, size_t ws_size,
                              hipStream_t stream) {
    const float* x = (const float*)d_in[0];
    const int* ei = (const int*)d_in[1];
    const float* W_lin = (const float*)d_in[2];
    const float* b_lin = (const float*)d_in[3];
    const float* W1s = (const float*)d_in[4];
    const float* gam = (const float*)d_in[5];
    const float* betp = (const float*)d_in[6];
    float* out = (float*)d_out;

    char* ws = (char*)d_ws;
    size_t off = 0;
    auto alloc = [&](size_t b) { size_t p = off; off = (off + b + 255) & ~(size_t)255; return p; };
    int* rp = (int*)(ws + alloc((size_t)(N_NODES + 1) * 4));
    int* cs = (int*)(ws + alloc((size_t)N_EDGES * 4));
    float* dinv = (float*)(ws + alloc((size_t)N_NODES * 4));
    int* hist = (int*)(ws + alloc((size_t)NBLK * NBUCK * 4));
    int* offsT = (int*)(ws + alloc((size_t)NBUCK * NBLK * 4));
    int* btot = (int*)(ws + alloc((size_t)NBUCK * 4));
    int* bbase = (int*)(ws + alloc((size_t)NBUCK * 4));
    unsigned int* buck = (unsigned int*)(ws + alloc((size_t)N_EDGES * 4));
    unsigned short* xb = (unsigned short*)(ws + alloc((size_t)N_NODES * D_IN * 2));
    unsigned short* xwb = (unsigned short*)(ws + alloc((size_t)N_NODES * D_HID * 2));
    unsigned short* x0b = (unsigned short*)(ws + alloc((size_t)N_NODES * D_HID * 2));
    unsigned short* zb = (unsigned short*)(ws + alloc((size_t)N_NODES * D_HID * 2));
    unsigned short* hb = (unsigned short*)(ws + alloc((size_t)N_NODES * D_HID * 2));
    unsigned short* Wlt = (unsigned short*)(ws + alloc((size_t)128 * 256 * 2));
    unsigned short* Wt = (unsigned short*)(ws + alloc((size_t)5 * 128 * 128 * 2));
    float* bns = (float*)(ws + alloc(256 * 4));
    float* st = (float*)(ws + alloc(256 * 4));

    const int ggrid = (N_NODES + 127) / 128;
    const int agrid = (N_NODES + 3) / 4;

    // CSR build (counting sort, coalesced writes)
    k_hist<<<NBLK, 256, 0, stream>>>(ei + N_EDGES, hist, N_EDGES);
    k_bkscan<<<NBUCK, 256, 0, stream>>>(hist, offsT, btot);
    k_bbase<<<1, 512, 0, stream>>>(btot, bbase, rp);
    k_scatter<<<NBLK, 256, 0, stream>>>(ei, ei + N_EDGES, offsT, bbase, buck, N_EDGES);
    k_csr<<<NBUCK, 256, 0, stream>>>(buck, bbase, btot, rp, dinv, cs);

    k_cast_x<<<(N_NODES * D_IN / 4 + 255) / 256, 256, 0, stream>>>((const float4*)x, (ushort2*)xb,
                                                                   N_NODES * D_IN / 4);
    k_prep_w<<<(128 * 256 + 5 * 128 * 128 + 255) / 256, 256, 0, stream>>>(W_lin, W1s, Wlt, Wt);

    // GCNConv
    k_mgemm<D_IN><<<ggrid, 256, 0, stream>>>(xb, Wlt, xwb, N_NODES);
    k_agg<0><<<agrid, 256, 0, stream>>>((const unsigned int*)xwb, nullptr, rp, cs, dinv, b_lin,
                                        nullptr, (unsigned int*)x0b, bns, N_NODES);

    // 5x GCN2Conv
    for (int i = 0; i < 5; ++i) {
        const unsigned short* zsrc = (i == 0) ? x0b : zb;
        if (i == 0)
            k_agg<1><<<agrid, 256, 0, stream>>>((const unsigned int*)zsrc, (const unsigned int*)x0b,
                                                rp, cs, nullptr, nullptr, nullptr,
                                                (unsigned int*)hb, bns, N_NODES);
        else
            k_agg<2><<<agrid, 256, 0, stream>>>((const unsigned int*)zsrc, (const unsigned int*)x0b,
                                                rp, cs, nullptr, nullptr, st,
                                                (unsigned int*)hb, bns, N_NODES);
        const unsigned short* W1 = Wt + (size_t)i * 128 * 128;
        if (i < 4) {
            k_lgemm<1><<<ggrid, 256, 0, stream>>>(hb, W1, zb, nullptr, bns, bns + 128, N_NODES);
            k_bn_fin<<<1, 128, 0, stream>>>(bns, bns + 128, gam + (size_t)i * 128,
                                            betp + (size_t)i * 128, st, N_NODES);
        } else {
            k_lgemm<2><<<ggrid, 256, 0, stream>>>(hb, W1, nullptr, out, nullptr, nullptr, N_NODES);
        }
    }
}